// Round 3
// baseline (153.935 us; speedup 1.0000x reference)
//
#include <hip/hip_runtime.h>
#include <hip/hip_bf16.h>

// Output row i (N = P*4 rows, D = 256 f32 each):
//   p = mapping[i]
//   last-of-group  <=> i == N-1 || mapping[i+1] != p
//   last  -> solvent_features[p]
//   else  -> monomer_features[i - p]   // monomer rank = i - (#lasts before i) = i - p
// Pure memory-bound gather (821 MB traffic, roofline ~130 us @ 6.3 TB/s).
// R3: same as R2 but with clang native vector type (ext_vector_type) so the
// nontemporal builtins compile. 4-way unroll for MLP + streaming hints.

typedef float f32x4 __attribute__((ext_vector_type(4)));

__device__ __forceinline__ f32x4 gather_one(const f32x4* __restrict__ mono,
                                            const f32x4* __restrict__ solv,
                                            const int*   __restrict__ mapping,
                                            long long t, int n_rows)
{
    const int i = (int)(t >> 6);      // output row (64 f32x4 per row)
    const int c = (int)(t & 63);      // f32x4 column within row
    const int p = mapping[i];
    const int inext = (i + 1 < n_rows) ? (i + 1) : i;
    const bool last = (i + 1 == n_rows) || (mapping[inext] != p);
    const f32x4* __restrict__ src =
        last ? (solv + (long long)p * 64)
             : (mono + (long long)(i - p) * 64);
    return __builtin_nontemporal_load(src + c);
}

__global__ void __launch_bounds__(256)
separated_gnn_gather(const f32x4* __restrict__ mono,    // [P*3 * 64]
                     const f32x4* __restrict__ solv,    // [P   * 64]
                     const int*   __restrict__ mapping, // [N]
                     f32x4*       __restrict__ out,     // [N * 64]
                     int n_rows)
{
    const long long total  = (long long)n_rows * 64;    // f32x4 elements
    const long long stride = (long long)gridDim.x * blockDim.x;
    long long t = (long long)blockIdx.x * blockDim.x + threadIdx.x;

    // Main: 4 independent iterations in flight (rows far apart -> no aliasing).
    for (; t + 3 * stride < total; t += 4 * stride) {
        const long long t0 = t;
        const long long t1 = t + stride;
        const long long t2 = t + 2 * stride;
        const long long t3 = t + 3 * stride;
        f32x4 v0 = gather_one(mono, solv, mapping, t0, n_rows);
        f32x4 v1 = gather_one(mono, solv, mapping, t1, n_rows);
        f32x4 v2 = gather_one(mono, solv, mapping, t2, n_rows);
        f32x4 v3 = gather_one(mono, solv, mapping, t3, n_rows);
        __builtin_nontemporal_store(v0, out + t0);
        __builtin_nontemporal_store(v1, out + t1);
        __builtin_nontemporal_store(v2, out + t2);
        __builtin_nontemporal_store(v3, out + t3);
    }
    // Tail.
    for (; t < total; t += stride) {
        f32x4 v = gather_one(mono, solv, mapping, t, n_rows);
        __builtin_nontemporal_store(v, out + t);
    }
}

extern "C" void kernel_launch(void* const* d_in, const int* in_sizes, int n_in,
                              void* d_out, int out_size, void* d_ws, size_t ws_size,
                              hipStream_t stream)
{
    const f32x4* mono    = (const f32x4*)d_in[0];   // monomer_features  [P*3, 256] f32
    const f32x4* solv    = (const f32x4*)d_in[1];   // solvent_features  [P,   256] f32
    const int*   mapping = (const int*)d_in[2];     // polymer_mapping   [N] int32
    f32x4*       out     = (f32x4*)d_out;           // [N, 256] f32

    const int n_rows = in_sizes[2];                 // N = 400000
    const long long total = (long long)n_rows * 64; // f32x4 count

    const int block = 256;
    long long want = (total + block - 1) / block;
    int grid = (int)(want < 2048 ? want : 2048);    // grid-stride the rest

    separated_gnn_gather<<<grid, block, 0, stream>>>(mono, solv, mapping, out, n_rows);
}

// Round 4
// 144.190 us; speedup vs baseline: 1.0676x; 1.0676x over previous
//
#include <hip/hip_runtime.h>
#include <hip/hip_bf16.h>

// Output row i (N = P*4 rows, D = 256 f32 each):
//   p = mapping[i]
//   last-of-group  <=> i == N-1 || mapping[i+1] != p
//   last  -> solvent_features[p]
//   else  -> monomer_features[i - p]   // monomer rank = i - (#lasts before i) = i - p
// Pure memory-bound gather (821 MB traffic, roofline ~130 us @ 6.3 TB/s).
// R4: group-of-4-adjacent-rows per wave -> each wave reads ~3KB contiguous
// mono + 1KB solv and writes 4KB contiguous (coarser stream granularity),
// mapping words for the chunk issued together. Per-row logic stays general.

typedef float f32x4 __attribute__((ext_vector_type(4)));

__global__ void __launch_bounds__(256)
separated_gnn_gather(const f32x4* __restrict__ mono,    // [P*3 * 64]
                     const f32x4* __restrict__ solv,    // [P   * 64]
                     const int*   __restrict__ mapping, // [N]
                     f32x4*       __restrict__ out,     // [N * 64]
                     int n_rows)
{
    const int lane    = threadIdx.x & 63;
    const long long wave    = ((long long)blockIdx.x * blockDim.x + threadIdx.x) >> 6;
    const long long n_waves = ((long long)gridDim.x * blockDim.x) >> 6;

    const int n_chunks = n_rows >> 2;          // 4 adjacent rows per wave-iter

    for (long long g = wave; g < n_chunks; g += n_waves) {
        const int base = (int)(g << 2);        // first row of chunk

        // Mapping words for rows base..base+4 (5 values, issued together).
        int m[5];
#pragma unroll
        for (int k = 0; k < 5; ++k) {
            const int idx = base + k;
            m[k] = (idx < n_rows) ? mapping[idx] : -1;   // -1 forces "last" at array end
        }

        // Per-row source addresses (general per-row logic; chunking is layout only).
        const f32x4* src[4];
#pragma unroll
        for (int k = 0; k < 4; ++k) {
            const int i = base + k;
            const int p = m[k];
            const bool last = (m[k + 1] != p);
            src[k] = last ? (solv + (long long)p * 64)
                          : (mono + (long long)(i - p) * 64);
        }

        // 4 independent 1KB loads (mono rows contiguous -> wave spans ~3KB+1KB).
        f32x4 v0 = __builtin_nontemporal_load(src[0] + lane);
        f32x4 v1 = __builtin_nontemporal_load(src[1] + lane);
        f32x4 v2 = __builtin_nontemporal_load(src[2] + lane);
        f32x4 v3 = __builtin_nontemporal_load(src[3] + lane);

        // 4KB contiguous store.
        f32x4* o = out + (long long)base * 64 + lane;
        __builtin_nontemporal_store(v0, o);
        __builtin_nontemporal_store(v1, o + 64);
        __builtin_nontemporal_store(v2, o + 128);
        __builtin_nontemporal_store(v3, o + 192);
    }

    // Generic tail for n_rows % 4 != 0 (empty for N = 400000).
    const long long tail_start = (long long)(n_chunks) * 4 * 64;
    const long long total     = (long long)n_rows * 64;
    const long long stride    = (long long)gridDim.x * blockDim.x;
    for (long long t = tail_start + (long long)blockIdx.x * blockDim.x + threadIdx.x;
         t < total; t += stride) {
        const int i = (int)(t >> 6);
        const int c = (int)(t & 63);
        const int p = mapping[i];
        const bool last = (i + 1 == n_rows) || (mapping[i + 1] != p);
        const f32x4* s = last ? (solv + (long long)p * 64)
                              : (mono + (long long)(i - p) * 64);
        __builtin_nontemporal_store(__builtin_nontemporal_load(s + c), out + t);
    }
}

extern "C" void kernel_launch(void* const* d_in, const int* in_sizes, int n_in,
                              void* d_out, int out_size, void* d_ws, size_t ws_size,
                              hipStream_t stream)
{
    const f32x4* mono    = (const f32x4*)d_in[0];   // monomer_features  [P*3, 256] f32
    const f32x4* solv    = (const f32x4*)d_in[1];   // solvent_features  [P,   256] f32
    const int*   mapping = (const int*)d_in[2];     // polymer_mapping   [N] int32
    f32x4*       out     = (f32x4*)d_out;           // [N, 256] f32

    const int n_rows = in_sizes[2];                 // N = 400000

    const int block = 256;
    const int grid  = 2048;                         // 8192 waves, grid-stride chunks

    separated_gnn_gather<<<grid, block, 0, stream>>>(mono, solv, mapping, out, n_rows);
}